// Round 9
// baseline (1144.368 us; speedup 1.0000x reference)
//
#include <hip/hip_runtime.h>

// ---------------- problem constants (fixed by setup_inputs) ----------------
constexpr int kH  = 48;
constexpr int kW  = 160;
constexpr int kP  = 7680;   // kH*kW
constexpr int kC  = 128;
constexpr int kNB = 64;
constexpr int kNH = 8;
constexpr int kNL = 6;

// workspace layout (in floats)
constexpr long long OFF_F1T = 0;
constexpr long long OFF_F2T = 983040;
constexpr long long OFF_F2  = 1966080;                 // F2hat f32 [b][pix][c]
constexpr long long OFF_MU  = OFF_F2 + 62914560LL;
constexpr long long OFF_SIG = OFF_MU + 491520LL;
constexpr long long OFF_WTS = OFF_SIG + 491520LL;
// per-layer folded weight block (element offsets, elements are 4 B):
// std matrices are f16 packed: [16 cchunk][128 d][4 u32]  (u32 = f16x2 along c)
// WKU: [8 h][128 c][8 u32]  (u32 = f16x2 along o)
constexpr int WSA2 = 0;
constexpr int WQ2  = 8192;
constexpr int WKU  = 16384;
constexpr int WV2  = 24576;
constexpr int WO2  = 32768;
constexpr int BSA  = 40960;    // f32 [128]
constexpr int BQ   = 41088;
constexpr int BK   = 41216;
constexpr int BV   = 41344;
constexpr int WTS_STRIDE = 41472;

// d_out regions (floats)
constexpr long long OUT_ATT  = 0;         // (1,48,160,64)
constexpr long long OUT_MASK = 491520;    // (64,1,48,160)
constexpr long long OUT_LC   = 983040;    // (1,48,160)
constexpr long long OUT_SSIM = 990720;    // (1,64,48,160)

// ---------------- helpers ----------------
typedef _Float16 h2v __attribute__((ext_vector_type(2)));
typedef __fp16 p2v __attribute__((ext_vector_type(2)));
typedef float f2v __attribute__((ext_vector_type(2)));
typedef __fp16 h8 __attribute__((ext_vector_type(8)));
typedef float fx16 __attribute__((ext_vector_type(16)));
union U32H2 { unsigned u; h2v h; };
union U32P2 { unsigned u; p2v h; };

__device__ __forceinline__ float fdot2(unsigned a, unsigned b, float c) {
  U32H2 ua; ua.u = a; U32H2 ub; ub.u = b;
  return __builtin_amdgcn_fdot2(ua.h, ub.h, c, false);
}
__device__ __forceinline__ unsigned pkrtz(float a, float b) {
  U32P2 t; t.h = __builtin_amdgcn_cvt_pkrtz(a, b); return t.u;
}
__device__ __forceinline__ f2v h2f(unsigned u) {
  U32P2 t; t.u = u; f2v r; r.x = (float)t.h.x; r.y = (float)t.h.y; return r;
}
__device__ __forceinline__ unsigned short f2h(float x) {
  U32P2 t; t.h = __builtin_amdgcn_cvt_pkrtz(x, 0.f); return (unsigned short)(t.u & 0xffffu);
}
// compiler-order pin for wave-internal LDS producer->consumer (HW LDS is in-order per wave)
__device__ __forceinline__ void wb() {
  __asm__ __volatile__("" ::: "memory");
  __builtin_amdgcn_wave_barrier();
  __asm__ __volatile__("" ::: "memory");
}

// ---------------- kernel 1: NCHW -> [pix][c] transpose of feat1/feat2 ----------------
__global__ void k_transpose(const float* __restrict__ feat1, const float* __restrict__ feat2,
                            float* __restrict__ f1t, float* __restrict__ f2t) {
  int idx = blockIdx.x * 256 + threadIdx.x;  // < 983040
  int pix = idx >> 7, c = idx & 127;
  f1t[idx] = feat1[c * kP + pix];
  f2t[idx] = feat2[c * kP + pix];
}

// ---------------- kernel 2: fold LN gamma/beta + combine SA Wo@Wv, pack f16 ----------------
__device__ __forceinline__ float redsum128(float v, float* red2) {
#pragma unroll
  for (int off = 32; off > 0; off >>= 1) v += __shfl_xor(v, off);
  int t = threadIdx.x;
  if ((t & 63) == 0) red2[t >> 6] = v;
  __syncthreads();
  float r = red2[0] + red2[1];
  __syncthreads();
  return r;
}

__global__ __launch_bounds__(128) void k_fold(
    const float* __restrict__ saw_, const float* __restrict__ sab_,
    const float* __restrict__ sow_, const float* __restrict__ sob_,
    const float* __restrict__ slg_, const float* __restrict__ slb_,
    const float* __restrict__ caw_, const float* __restrict__ cab_,
    const float* __restrict__ clg_, const float* __restrict__ clb_,
    const float* __restrict__ cow_, float* __restrict__ wts) {
  int i = blockIdx.x >> 7, d = blockIdx.x & 127, c = threadIdx.x;
  const float* saw = saw_ + (long long)i * 384 * kC;
  const float* sab = sab_ + i * 384;
  const float* sow = sow_ + i * kC * kC;
  const float* sob = sob_ + i * kC;
  const float* slg = slg_ + i * kC;
  const float* slb = slb_ + i * kC;
  const float* caw = caw_ + (long long)i * 384 * kC;
  const float* cab = cab_ + i * 384;
  const float* clg = clg_ + i * kC;
  const float* clb = clb_ + i * kC;
  const float* cow = cow_ + i * kC * kC;
  float* WL = wts + (long long)i * WTS_STRIDE;
  __shared__ float red2[2];

  int jstd = (c >> 3) * 1024 + d * 8 + (c & 7);  // std matrix u16 index for (c,d)

  // ---- SA: Wsa_pre = Wo_sa @ Wv_sa, fold ln gamma/beta ----
  float acc = 0.f;
  for (int m = 0; m < kC; m++) acc += sow[d * kC + m] * saw[(256 + m) * kC + c];
  float t1 = redsum128(acc * slb[c] + sow[d * kC + c] * sab[256 + c], red2);
  if (c == 0) WL[BSA + d] = t1 + sob[d];
  ((unsigned short*)(WL + WSA2))[jstd] = f2h(acc * slg[c]);

  // ---- Q (x0.25 fold) ----
  float wq = caw[d * kC + c];
  float t2 = redsum128(wq * clb[c], red2);
  if (c == 0) WL[BQ + d] = 0.25f * (t2 + cab[d]);
  ((unsigned short*)(WL + WQ2))[jstd] = f2h(0.25f * wq * clg[c]);

  // ---- K -> WKU [h][c][o-pairs] ----
  float wk = caw[(kC + d) * kC + c];
  float t3 = redsum128(wk * clb[c], red2);
  if (c == 0) WL[BK + d] = t3 + cab[kC + d];
  {
    int h = d >> 4, o = d & 15;
    ((unsigned short*)(WL + WKU))[h * 2048 + c * 16 + o] = f2h(wk * clg[c]);
  }

  // ---- V ----
  float wv = caw[(2 * kC + d) * kC + c];
  float t4 = redsum128(wv * clb[c], red2);
  if (c == 0) WL[BV + d] = t4 + cab[2 * kC + d];
  ((unsigned short*)(WL + WV2))[jstd] = f2h(wv * clg[c]);

  // ---- O (no fold, just pack) ----
  ((unsigned short*)(WL + WO2))[jstd] = f2h(cow[d * kC + c]);
}

// ---------------- kernel 3: bilinear warp + per-(bin,pixel) LN stats + nearest mask ----------------
// b0: bin-chunk offset (launched in 32-bin chunks so k_ssim reads an L2/L3-hot F2 slice)
__global__ __launch_bounds__(256) void k_warp(const float* __restrict__ f2t,
                                              const float* __restrict__ coords,
                                              float* __restrict__ F2, float* __restrict__ mu,
                                              float* __restrict__ sig, float* __restrict__ maskout,
                                              int b0) {
  int wave = threadIdx.x >> 6, lane = threadIdx.x & 63;
  int pix = blockIdx.x * 4 + wave;
  int b = b0 + blockIdx.y;
  long long bp = (long long)b * kP + pix;
  float cx = coords[bp * 2], cy = coords[bp * 2 + 1];
  cx = (cx < -1.f) ? -2.f : cx;
  cx = (cx > 1.f) ? 2.f : cx;
  cy = (cy < -1.f) ? -2.f : cy;
  cy = (cy > 1.f) ? 2.f : cy;
  float gx = (cx + 1.f) * 0.5f * (float)(kW - 1);
  float gy = (cy + 1.f) * 0.5f * (float)(kH - 1);
  float x0f = floorf(gx), y0f = floorf(gy);
  float wx = gx - x0f, wy = gy - y0f;
  int x0 = (int)x0f, y0 = (int)y0f;
  int x1 = x0 + 1, y1 = y0 + 1;
  float vx0 = (x0 >= 0 && x0 < kW) ? 1.f : 0.f;
  float vx1 = (x1 >= 0 && x1 < kW) ? 1.f : 0.f;
  float vy0 = (y0 >= 0 && y0 < kH) ? 1.f : 0.f;
  float vy1 = (y1 >= 0 && y1 < kH) ? 1.f : 0.f;
  int x0c = min(max(x0, 0), kW - 1), x1c = min(max(x1, 0), kW - 1);
  int y0c = min(max(y0, 0), kH - 1), y1c = min(max(y1, 0), kH - 1);
  float w00 = (1.f - wy) * (1.f - wx) * vx0 * vy0;
  float w01 = (1.f - wy) * wx * vx1 * vy0;
  float w10 = wy * (1.f - wx) * vx0 * vy1;
  float w11 = wy * wx * vx1 * vy1;
  const float2* r00 = (const float2*)(f2t + (y0c * kW + x0c) * kC);
  const float2* r01 = (const float2*)(f2t + (y0c * kW + x1c) * kC);
  const float2* r10 = (const float2*)(f2t + (y1c * kW + x0c) * kC);
  const float2* r11 = (const float2*)(f2t + (y1c * kW + x1c) * kC);
  float2 g00 = r00[lane], g01 = r01[lane], g10 = r10[lane], g11 = r11[lane];
  float v0 = w00 * g00.x + w01 * g01.x + w10 * g10.x + w11 * g11.x;
  float v1 = w00 * g00.y + w01 * g01.y + w10 * g10.y + w11 * g11.y;
  float s = v0 + v1, s2 = v0 * v0 + v1 * v1;
#pragma unroll
  for (int off = 32; off > 0; off >>= 1) {
    s += __shfl_xor(s, off);
    s2 += __shfl_xor(s2, off);
  }
  float m = s * (1.f / 128.f);
  float var = s2 * (1.f / 128.f) - m * m;
  float rs = rsqrtf(var + 1e-5f);
  float2 o;
  o.x = (v0 - m) * rs;
  o.y = (v1 - m) * rs;
  ((float2*)(F2 + bp * kC))[lane] = o;
  if (lane == 0) {
    mu[bp] = m;
    sig[bp] = sqrtf(var + 1e-5f);
    int xi = (int)rintf(gx), yi = (int)rintf(gy);
    maskout[bp] = (xi >= 0 && xi < kW && yi >= 0 && yi < kH) ? 1.f : 0.f;
  }
}

// ---------------- kernel 4: SSIM volume, rolling 3x3 column sums ----------------
__global__ __launch_bounds__(256) void k_ssim(const float* __restrict__ f1t,
                                              const float* __restrict__ F2,
                                              const float* __restrict__ mu,
                                              const float* __restrict__ sig,
                                              float* __restrict__ ssimout, int b0) {
  const int lane = threadIdx.x & 63;
  const int y = blockIdx.x * 4 + (threadIdx.x >> 6);
  const int b = b0 + blockIdx.y;
  const int ym = (y == 0) ? 1 : y - 1;
  const int yp = (y == kH - 1) ? kH - 2 : y + 1;
  const long long bb = (long long)b * kP;
  const float* f1m = f1t + (ym * kW) * kC + 2 * lane;
  const float* f10 = f1t + (y * kW) * kC + 2 * lane;
  const float* f1p = f1t + (yp * kW) * kC + 2 * lane;
  const float* F2m = F2 + (bb + ym * kW) * kC + 2 * lane;
  const float* F20 = F2 + (bb + y * kW) * kC + 2 * lane;
  const float* F2p = F2 + (bb + yp * kW) * kC + 2 * lane;
  const float* mum = mu + bb + ym * kW;
  const float* mu0 = mu + bb + y * kW;
  const float* mup = mu + bb + yp * kW;
  const float* sgm = sig + bb + ym * kW;
  const float* sg0 = sig + bb + y * kW;
  const float* sgp = sig + bb + yp * kW;
  float* outrow = ssimout + bb + y * kW;

  f2v C[3][5];

  auto colsum = [&](int x, f2v* Cc) {
    f2v am = *(const f2v*)(f1m + (size_t)x * kC);
    f2v a0 = *(const f2v*)(f10 + (size_t)x * kC);
    f2v ap = *(const f2v*)(f1p + (size_t)x * kC);
    f2v fm = *(const f2v*)(F2m + (size_t)x * kC);
    f2v f0 = *(const f2v*)(F20 + (size_t)x * kC);
    f2v fp = *(const f2v*)(F2p + (size_t)x * kC);
    f2v wm = fm * sgm[x] + mum[x];
    f2v w0 = f0 * sg0[x] + mu0[x];
    f2v wp = fp * sgp[x] + mup[x];
    Cc[0] = am + a0 + ap;
    Cc[1] = wm + w0 + wp;
    Cc[2] = am * am + a0 * a0 + ap * ap;
    Cc[3] = wm * wm + w0 * w0 + wp * wp;
    Cc[4] = am * wm + a0 * w0 + ap * wp;
  };

  auto emit = [&](int xo, f2v s0, f2v s1, f2v s2, f2v s3, f2v s4) {
    const float inv9 = 1.f / 9.f;
    f2v mx = s0 * inv9, my = s1 * inv9;
    f2v vx = s2 * inv9 - mx * mx;
    f2v vy = s3 * inv9 - my * my;
    f2v vxy = s4 * inv9 - mx * my;
    f2v num = (2.f * mx * my + 1e-4f) * (2.f * vxy + 9e-4f);
    f2v den = (mx * mx + my * my + 1e-4f) * (vx + vy + 9e-4f);
    f2v val = (1.f - num / den) * 0.5f;
    float t = fminf(fmaxf(val.x, 0.f), 1.f) + fminf(fmaxf(val.y, 0.f), 1.f);
#pragma unroll
    for (int o = 32; o > 0; o >>= 1) t += __shfl_xor(t, o);
    if (lane == 0) outrow[xo] = t * (1.f / 128.f);
  };

  colsum(0, C[0]);
  colsum(1, C[1]);
  emit(0, C[0][0] + 2.f * C[1][0], C[0][1] + 2.f * C[1][1], C[0][2] + 2.f * C[1][2],
       C[0][3] + 2.f * C[1][3], C[0][4] + 2.f * C[1][4]);
#pragma unroll 3
  for (int x = 2; x < kW; ++x) {
    colsum(x, C[x % 3]);
    emit(x - 1, C[0][0] + C[1][0] + C[2][0], C[0][1] + C[1][1] + C[2][1],
         C[0][2] + C[1][2] + C[2][2], C[0][3] + C[1][3] + C[2][3],
         C[0][4] + C[1][4] + C[2][4]);
  }
  emit(kW - 1, C[0][0] + 2.f * C[2][0], C[0][1] + 2.f * C[2][1], C[0][2] + 2.f * C[2][2],
       C[0][3] + 2.f * C[2][3], C[0][4] + 2.f * C[2][4]);
}

// ---------------- kernel 5: argmin over bins -> lowest_cost ----------------
__global__ __launch_bounds__(256) void k_argmin(const float* __restrict__ ssim,
                                                float* __restrict__ lc) {
  int pix = blockIdx.x * 256 + threadIdx.x;  // 7680 exact
  float best = ssim[pix];
  int bi = 0;
  for (int b = 1; b < kNB; b++) {
    float v = ssim[b * kP + pix];
    if (v < best) { best = v; bi = b; }
  }
  float depth = expf(-0.69314718f + (5.2983174f * (float)bi) / 63.0f);
  lc[pix] = 1.f / depth;
}

// ---------------- kernel 6: fused 6-layer transformer, 1 pixel / wave, no barriers ----
// (unchanged from round 8: MFMA scores + u ^4h swizzle; ~L2-stream/VALU co-limited)

__device__ __forceinline__ f2v gemmW(int l, const unsigned* __restrict__ inb,
                                     const unsigned* __restrict__ W, float b0, float b1) {
  float a0 = b0, a1 = b1, c0 = 0.f, c1 = 0.f;  // 4 chains (even/odd j-chunks)
  const unsigned* wp = W + l * 8;
#pragma unroll
  for (int j = 0; j < 16; j += 2) {
    uint4 inA = *(const uint4*)(inb + 4 * j);
    uint4 inB = *(const uint4*)(inb + 4 * j + 4);
    uint4 wa = *(const uint4*)(wp + j * 512);
    uint4 wc = *(const uint4*)(wp + j * 512 + 4);
    uint4 wa2 = *(const uint4*)(wp + j * 512 + 512);
    uint4 wc2 = *(const uint4*)(wp + j * 512 + 516);
    a0 = fdot2(inA.x, wa.x, a0);  a0 = fdot2(inA.y, wa.y, a0);
    a0 = fdot2(inA.z, wa.z, a0);  a0 = fdot2(inA.w, wa.w, a0);
    a1 = fdot2(inA.x, wc.x, a1);  a1 = fdot2(inA.y, wc.y, a1);
    a1 = fdot2(inA.z, wc.z, a1);  a1 = fdot2(inA.w, wc.w, a1);
    c0 = fdot2(inB.x, wa2.x, c0); c0 = fdot2(inB.y, wa2.y, c0);
    c0 = fdot2(inB.z, wa2.z, c0); c0 = fdot2(inB.w, wa2.w, c0);
    c1 = fdot2(inB.x, wc2.x, c1); c1 = fdot2(inB.y, wc2.y, c1);
    c1 = fdot2(inB.z, wc2.z, c1); c1 = fdot2(inB.w, wc2.w, c1);
  }
  f2v r; r.x = a0 + c0; r.y = a1 + c1; return r;
}

__device__ __forceinline__ void ln_store(int l, f2v X, unsigned* xhq) {
  float s = X.x + X.y, s2 = X.x * X.x + X.y * X.y;
#pragma unroll
  for (int o = 32; o > 0; o >>= 1) { s += __shfl_xor(s, o); s2 += __shfl_xor(s2, o); }
  float m = s * 0.0078125f;
  float var = s2 * 0.0078125f - m * m;
  float rs = rsqrtf(var + 1e-5f);
  xhq[l] = pkrtz((X.x - m) * rs, (X.y - m) * rs);
}

__global__ __launch_bounds__(64) void k_attn(const float* __restrict__ F2g,
                                             const float* __restrict__ f1t,
                                             const float* __restrict__ wts,
                                             const float* __restrict__ cab_out,
                                             float* __restrict__ attn_out) {
  // F2s: [64 bins][64 u32 f16x2], XOR-swizzled: phys col = col ^ (4*(bin&15))
  __shared__ __align__(16) unsigned F2s[64 * 64];
  // upb: u (f16x2 [8h][64], col ^ 4h) -> p (f32 [64b][8h]) / rawh -> wbar ([8h][64], col ^ 4h)
  __shared__ __align__(16) unsigned upb[512];
  __shared__ __align__(16) unsigned xhq[64];  // xhat, later q (f16x2 c-pairs)

  const int l = threadIdx.x;
  const int pix = blockIdx.x;

  // ---- load this pixel's F2hat (f32 global) -> f16x2 swizzled LDS ----
  {
#pragma unroll 4
    for (int r = 0; r < 64; ++r) {
      float2 v = *(const float2*)(F2g + ((long long)r * kP + pix) * kC + 2 * l);
      F2s[r * 64 + (l ^ (4 * (r & 15)))] = pkrtz(v.x, v.y);
    }
  }
  f2v X;
  { float2 xv = ((const float2*)(f1t + (long long)pix * kC))[l]; X.x = xv.x; X.y = xv.y; }
  wb();

  float chsum = 0.f;
  float* pf = (float*)upb;
  const int mrow = l & 31;   // bin row within tile (also MFMA C col = head for n<8)
  const int kg = l >> 5;     // MFMA k-group
  const int rbase = 4 * kg;  // MFMA C row base

  for (int ly = 0; ly < kNL; ++ly) {
    const float* WL = wts + (long long)ly * WTS_STRIDE;

    // ---- LN(SA) -> xhq ; SA gemm ; residual ----
    ln_store(l, X, xhq);
    wb();
    {
      float2 bv = ((const float2*)(WL + BSA))[l];
      f2v o = gemmW(l, xhq, (const unsigned*)(WL + WSA2), bv.x, bv.y);
      X += o;
    }
    wb();
    // ---- LN(CA) -> xhq ; Q gemm ----
    ln_store(l, X, xhq);
    wb();
    f2v q;
    {
      float2 bv = ((const float2*)(WL + BQ))[l];
      q = gemmW(l, xhq, (const unsigned*)(WL + WQ2), bv.x, bv.y);
    }
    if (ly == kNL - 1) {  // k-bias contribution to raw: full dot q.bk
      float2 bk = ((const float2*)(WL + BK))[l];
      float cp = q.x * bk.x + q.y * bk.y;
#pragma unroll
      for (int o = 32; o > 0; o >>= 1) cp += __shfl_xor(cp, o);
      chsum = cp;
    }
    xhq[l] = pkrtz(q.x, q.y);  // qpk (d-pairs == o-pairs)
    wb();

    // ---- U: u[h][c-pair l] = sum_o q[h*16+o] * Wk'[h*16+o][c]; store col ^ 4h ----
    {
      const unsigned* KU = (const unsigned*)(WL + WKU);
#pragma unroll
      for (int h = 0; h < kNH; ++h) {
        uint4 q0 = *(const uint4*)(xhq + h * 8);      // o-pairs 0..3 (broadcast)
        uint4 q1 = *(const uint4*)(xhq + h * 8 + 4);  // o-pairs 4..7
        const unsigned* w0 = KU + (h * 128 + 2 * l) * 8;
        uint4 a0 = ((const uint4*)w0)[0], a1 = ((const uint4*)w0)[1];
        uint4 b0 = ((const uint4*)w0)[2], b1 = ((const uint4*)w0)[3];  // c = 2l+1
        float u0 = 0.f, u1 = 0.f, u2 = 0.f, u3 = 0.f;
        u0 = fdot2(q0.x, a0.x, u0); u0 = fdot2(q0.y, a0.y, u0);
        u0 = fdot2(q0.z, a0.z, u0); u0 = fdot2(q0.w, a0.w, u0);
        u2 = fdot2(q1.x, a1.x, u2); u2 = fdot2(q1.y, a1.y, u2);
        u2 = fdot2(q1.z, a1.z, u2); u2 = fdot2(q1.w, a1.w, u2);
        u1 = fdot2(q0.x, b0.x, u1); u1 = fdot2(q0.y, b0.y, u1);
        u1 = fdot2(q0.z, b0.z, u1); u1 = fdot2(q0.w, b0.w, u1);
        u3 = fdot2(q1.x, b1.x, u3); u3 = fdot2(q1.y, b1.y, u3);
        u3 = fdot2(q1.z, b1.z, u3); u3 = fdot2(q1.w, b1.w, u3);
        upb[h * 64 + (l ^ (4 * h))] = pkrtz(u0 + u2, u1 + u3);
      }
    }
    wb();

    // ---- scores via MFMA: C[bin][head] = F2[64x128] @ u[128x8] ----
    fx16 acc0 = (fx16)0.f, acc1 = (fx16)0.f;
    {
      const int hn = mrow & 7;          // clamp head for n>=8 lanes (dup cols, ignored)
      const int sw = 4 * (mrow & 15);   // same swizzle for bin and bin+32
      const int usw = 4 * hn;           // u row swizzle
#pragma unroll
      for (int kc = 0; kc < 8; ++kc) {
        const int cp = kc * 8 + kg * 4;  // u32 column of channel k0 = kc*16+kg*8
        h8 Bv = *(const h8*)(upb + hn * 64 + (cp ^ usw));
        h8 A0 = *(const h8*)(F2s + mrow * 64 + (cp ^ sw));
        h8 A1 = *(const h8*)(F2s + (mrow + 32) * 64 + (cp ^ sw));
        acc0 = __builtin_amdgcn_mfma_f32_32x32x16_f16(A0, Bv, acc0, 0, 0, 0);
        acc1 = __builtin_amdgcn_mfma_f32_32x32x16_f16(A1, Bv, acc1, 0, 0, 0);
      }
    }
    if (ly == kNL - 1) {
      // raw[bin] = sum_h sc[bin][h] + chsum; redistribute via pf as rawh[8][64]
      wb();
      if (mrow < 8) {
#pragma unroll
        for (int r = 0; r < 16; ++r) {
          int row = (r & 3) + 8 * (r >> 2) + rbase;
          pf[mrow * 64 + row] = acc0[r];
          pf[mrow * 64 + 32 + row] = acc1[r];
        }
      }
      wb();
      float rsum = chsum;
#pragma unroll
      for (int h = 0; h < kNH; ++h) rsum += pf[h * 64 + l];
      attn_out[(long long)pix * 64 + l] = rsum;
      return;
    }
    // ---- softmax over bins: head h lives in lanes {h, h+32} (16+16 rows each) ----
    {
      float mx = acc0[0];
#pragma unroll
      for (int r = 0; r < 16; ++r) { mx = fmaxf(mx, acc0[r]); mx = fmaxf(mx, acc1[r]); }
      mx = fmaxf(mx, __shfl_xor(mx, 32));
      float pv0[16], pv1[16];
      float sm = 0.f;
#pragma unroll
      for (int r = 0; r < 16; ++r) {
        pv0[r] = __expf(acc0[r] - mx); sm += pv0[r];
        pv1[r] = __expf(acc1[r] - mx); sm += pv1[r];
      }
      sm += __shfl_xor(sm, 32);
      float inv = 1.f / sm;
      wb();  // all u (B-frag) reads complete before pf overwrites upb
      if (mrow < 8) {
#pragma unroll
        for (int r = 0; r < 16; ++r) {
          int row = (r & 3) + 8 * (r >> 2) + rbase;
          pf[row * 8 + mrow] = pv0[r] * inv;
          pf[(32 + row) * 8 + mrow] = pv1[r] * inv;
        }
      }
    }
    wb();
    // ---- wbar[h][c] = sum_b p[b][h]*F2[b][c]; lane owns 4 ch, half-wave owns 32 bins ----
    {
      const int half = l >> 5, lb = l & 31;
      f2v wA[8], wB[8];
#pragma unroll
      for (int h = 0; h < kNH; ++h) { wA[h] = (f2v)0.f; wB[h] = (f2v)0.f; }
#pragma unroll 2
      for (int t = 0; t < 32; ++t) {
        int b = half * 32 + t;
        uint2 fv = *(const uint2*)(F2s + b * 64 + ((2 * lb) ^ (4 * (b & 15))));
        f2v fA = h2f(fv.x), fB = h2f(fv.y);
        float4 pA = *(const float4*)(pf + b * 8);
        float4 pB = *(const float4*)(pf + b * 8 + 4);
        wA[0] += fA * pA.x; wB[0] += fB * pA.x;
        wA[1] += fA * pA.y; wB[1] += fB * pA.y;
        wA[2] += fA * pA.z; wB[2] += fB * pA.z;
        wA[3] += fA * pA.w; wB[3] += fB * pA.w;
        wA[4] += fA * pB.x; wB[4] += fB * pB.x;
        wA[5] += fA * pB.y; wB[5] += fB * pB.y;
        wA[6] += fA * pB.z; wB[6] += fB * pB.z;
        wA[7] += fA * pB.w; wB[7] += fB * pB.w;
      }
      // combine halves
#pragma unroll
      for (int h = 0; h < kNH; ++h) {
        wA[h].x += __shfl_xor(wA[h].x, 32);
        wA[h].y += __shfl_xor(wA[h].y, 32);
        wB[h].x += __shfl_xor(wB[h].x, 32);
        wB[h].y += __shfl_xor(wB[h].y, 32);
      }
      wb();
      // write packed wbar into upb ([8h][64], col swizzle ^ 4h); halves split h-ranges
#pragma unroll
      for (int hh = 0; hh < 4; ++hh) {
        int h = half * 4 + hh;
        uint2 pk;
        pk.x = pkrtz(wA[h].x, wA[h].y);
        pk.y = pkrtz(wB[h].x, wB[h].y);
        *(uint2*)(upb + h * 64 + ((2 * lb) ^ (4 * h))) = pk;
      }
    }
    wb();
    // ---- AO: ao[d] = wbar[h(d)] . Wv'[:,d] + bv (4 chains) ----
    {
      const int h = l >> 3;  // d=2l -> head
      const unsigned* wrow = upb + h * 64;
      const unsigned* WV = (const unsigned*)(WL + WV2) + l * 8;
      float2 bv = ((const float2*)(WL + BV))[l];
      float a0 = bv.x, a1 = bv.y, c0 = 0.f, c1 = 0.f;
      const int sw = 4 * h;
#pragma unroll
      for (int j = 0; j < 16; j += 2) {
        uint4 inA = *(const uint4*)(wrow + ((4 * j) ^ sw));
        uint4 inB = *(const uint4*)(wrow + ((4 * j + 4) ^ sw));
        uint4 wa = *(const uint4*)(WV + j * 512);
        uint4 wc = *(const uint4*)(WV + j * 512 + 4);
        uint4 wa2 = *(const uint4*)(WV + j * 512 + 512);
        uint4 wc2 = *(const uint4*)(WV + j * 512 + 516);
        a0 = fdot2(inA.x, wa.x, a0);  a0 = fdot2(inA.y, wa.y, a0);
        a0 = fdot2(inA.z, wa.z, a0);  a0 = fdot2(inA.w, wa.w, a0);
        a1 = fdot2(inA.x, wc.x, a1);  a1 = fdot2(inA.y, wc.y, a1);
        a1 = fdot2(inA.z, wc.z, a1);  a1 = fdot2(inA.w, wc.w, a1);
        c0 = fdot2(inB.x, wa2.x, c0); c0 = fdot2(inB.y, wa2.y, c0);
        c0 = fdot2(inB.z, wa2.z, c0); c0 = fdot2(inB.w, wa2.w, c0);
        c1 = fdot2(inB.x, wc2.x, c1); c1 = fdot2(inB.y, wc2.y, c1);
        c1 = fdot2(inB.z, wc2.z, c1); c1 = fdot2(inB.w, wc2.w, c1);
      }
      xhq[l] = pkrtz(a0 + c0, a1 + c1);
    }
    wb();
    // ---- O: X += ao @ Wo^T + bo ----
    {
      float2 bv = ((const float2*)(cab_out + ly * kC))[l];
      f2v o = gemmW(l, xhq, (const unsigned*)(WL + WO2), bv.x, bv.y);
      X += o;
    }
    wb();
  }
}

// ---------------- launch ----------------
extern "C" void kernel_launch(void* const* d_in, const int* in_sizes, int n_in, void* d_out,
                              int out_size, void* d_ws, size_t ws_size, hipStream_t stream) {
  (void)in_sizes; (void)n_in; (void)out_size; (void)ws_size;
  const float* feat1 = (const float*)d_in[0];
  const float* feat2 = (const float*)d_in[1];
  const float* coords = (const float*)d_in[2];
  const float* sa_in_w = (const float*)d_in[3];
  const float* sa_in_b = (const float*)d_in[4];
  const float* sa_out_w = (const float*)d_in[5];
  const float* sa_out_b = (const float*)d_in[6];
  const float* sa_ln_g = (const float*)d_in[7];
  const float* sa_ln_b = (const float*)d_in[8];
  const float* ca_in_w = (const float*)d_in[9];
  const float* ca_in_b = (const float*)d_in[10];
  const float* ca_out_w = (const float*)d_in[11];
  const float* ca_out_b = (const float*)d_in[12];
  const float* ca_ln_g = (const float*)d_in[13];
  const float* ca_ln_b = (const float*)d_in[14];

  float* out = (float*)d_out;
  float* ws = (float*)d_ws;
  float* f1t = ws + OFF_F1T;
  float* f2t = ws + OFF_F2T;
  float* F2 = ws + OFF_F2;
  float* mu = ws + OFF_MU;
  float* sig = ws + OFF_SIG;
  float* wts = ws + OFF_WTS;

  float* att = out + OUT_ATT;
  float* mask = out + OUT_MASK;
  float* lc = out + OUT_LC;
  float* ssim = out + OUT_SSIM;

  k_transpose<<<3840, 256, 0, stream>>>(feat1, feat2, f1t, f2t);
  k_fold<<<kNL * 128, 128, 0, stream>>>(sa_in_w, sa_in_b, sa_out_w, sa_out_b, sa_ln_g, sa_ln_b,
                                        ca_in_w, ca_in_b, ca_ln_g, ca_ln_b, ca_out_w, wts);
  // Bin-chunked warp->ssim so ssim reads an L2/L3-hot 126 MB F2 slice (bit-identical math).
  dim3 gw(1920, 32);
  dim3 gs(12, 32);
  k_warp<<<gw, 256, 0, stream>>>(f2t, coords, F2, mu, sig, mask, 0);
  k_ssim<<<gs, 256, 0, stream>>>(f1t, F2, mu, sig, ssim, 0);
  k_warp<<<gw, 256, 0, stream>>>(f2t, coords, F2, mu, sig, mask, 32);
  k_ssim<<<gs, 256, 0, stream>>>(f1t, F2, mu, sig, ssim, 32);
  k_argmin<<<30, 256, 0, stream>>>(ssim, lc);
  k_attn<<<kP, 64, 0, stream>>>(F2, f1t, wts, ca_out_b, att);
}

// Round 10
// 732.161 us; speedup vs baseline: 1.5630x; 1.5630x over previous
//
#include <hip/hip_runtime.h>

// ---------------- problem constants (fixed by setup_inputs) ----------------
constexpr int kH  = 48;
constexpr int kW  = 160;
constexpr int kP  = 7680;   // kH*kW
constexpr int kC  = 128;
constexpr int kNB = 64;
constexpr int kNH = 8;
constexpr int kNL = 6;

// workspace layout (in floats)
constexpr long long OFF_F1T = 0;
constexpr long long OFF_F2T = 983040;
constexpr long long OFF_F2  = 1966080;                 // F2hat f32 [b][pix][c]
constexpr long long OFF_MU  = OFF_F2 + 62914560LL;
constexpr long long OFF_SIG = OFF_MU + 491520LL;
constexpr long long OFF_WTS = OFF_SIG + 491520LL;
// per-layer folded weight block (element offsets, elements are 4 B):
// std matrices are f16 packed: [16 cchunk][128 d][4 u32]  (u32 = f16x2 along c)
// WKU: [8 h][128 c][8 u32]  (u32 = f16x2 along o)
constexpr int WSA2 = 0;
constexpr int WQ2  = 8192;
constexpr int WKU  = 16384;
constexpr int WV2  = 24576;
constexpr int WO2  = 32768;
constexpr int BSA  = 40960;    // f32 [128]
constexpr int BQ   = 41088;
constexpr int BK   = 41216;
constexpr int BV   = 41344;
constexpr int WTS_STRIDE = 41472;

// d_out regions (floats)
constexpr long long OUT_ATT  = 0;         // (1,48,160,64)
constexpr long long OUT_MASK = 491520;    // (64,1,48,160)
constexpr long long OUT_LC   = 983040;    // (1,48,160)
constexpr long long OUT_SSIM = 990720;    // (1,64,48,160)

// ---------------- helpers ----------------
typedef _Float16 h2v __attribute__((ext_vector_type(2)));
typedef __fp16 p2v __attribute__((ext_vector_type(2)));
typedef float f2v __attribute__((ext_vector_type(2)));
typedef __fp16 h8 __attribute__((ext_vector_type(8)));
typedef float fx16 __attribute__((ext_vector_type(16)));
union U32H2 { unsigned u; h2v h; };
union U32P2 { unsigned u; p2v h; };

__device__ __forceinline__ float fdot2(unsigned a, unsigned b, float c) {
  U32H2 ua; ua.u = a; U32H2 ub; ub.u = b;
  return __builtin_amdgcn_fdot2(ua.h, ub.h, c, false);
}
__device__ __forceinline__ unsigned pkrtz(float a, float b) {
  U32P2 t; t.h = __builtin_amdgcn_cvt_pkrtz(a, b); return t.u;
}
__device__ __forceinline__ f2v h2f(unsigned u) {
  U32P2 t; t.u = u; f2v r; r.x = (float)t.h.x; r.y = (float)t.h.y; return r;
}
__device__ __forceinline__ unsigned short f2h(float x) {
  U32P2 t; t.h = __builtin_amdgcn_cvt_pkrtz(x, 0.f); return (unsigned short)(t.u & 0xffffu);
}
// compiler-order pin for wave-internal LDS producer->consumer (HW LDS is in-order per wave)
__device__ __forceinline__ void wb() {
  __asm__ __volatile__("" ::: "memory");
  __builtin_amdgcn_wave_barrier();
  __asm__ __volatile__("" ::: "memory");
}

// ---------------- kernel 1: NCHW -> [pix][c] transpose, LDS-tiled (coalesced both ways) ----
__global__ __launch_bounds__(256) void k_transpose(const float* __restrict__ feat1,
                                                   const float* __restrict__ feat2,
                                                   float* __restrict__ f1t,
                                                   float* __restrict__ f2t) {
  __shared__ float t1[32][33], t2[32][33];
  const int p0 = blockIdx.x * 32, c0 = blockIdx.y * 32;
  const int r = threadIdx.x >> 5, col = threadIdx.x & 31;
#pragma unroll
  for (int rr = r; rr < 32; rr += 8) {
    t1[rr][col] = feat1[(c0 + rr) * kP + p0 + col];
    t2[rr][col] = feat2[(c0 + rr) * kP + p0 + col];
  }
  __syncthreads();
#pragma unroll
  for (int rr = r; rr < 32; rr += 8) {
    f1t[(p0 + rr) * kC + c0 + col] = t1[col][rr];
    f2t[(p0 + rr) * kC + c0 + col] = t2[col][rr];
  }
}

// ---------------- kernel 2: fold LN gamma/beta + combine SA Wo@Wv, pack f16 ----------------
__device__ __forceinline__ float redsum128(float v, float* red2) {
#pragma unroll
  for (int off = 32; off > 0; off >>= 1) v += __shfl_xor(v, off);
  int t = threadIdx.x;
  if ((t & 63) == 0) red2[t >> 6] = v;
  __syncthreads();
  float r = red2[0] + red2[1];
  __syncthreads();
  return r;
}

__global__ __launch_bounds__(128) void k_fold(
    const float* __restrict__ saw_, const float* __restrict__ sab_,
    const float* __restrict__ sow_, const float* __restrict__ sob_,
    const float* __restrict__ slg_, const float* __restrict__ slb_,
    const float* __restrict__ caw_, const float* __restrict__ cab_,
    const float* __restrict__ clg_, const float* __restrict__ clb_,
    const float* __restrict__ cow_, float* __restrict__ wts) {
  int i = blockIdx.x >> 7, d = blockIdx.x & 127, c = threadIdx.x;
  const float* saw = saw_ + (long long)i * 384 * kC;
  const float* sab = sab_ + i * 384;
  const float* sow = sow_ + i * kC * kC;
  const float* sob = sob_ + i * kC;
  const float* slg = slg_ + i * kC;
  const float* slb = slb_ + i * kC;
  const float* caw = caw_ + (long long)i * 384 * kC;
  const float* cab = cab_ + i * 384;
  const float* clg = clg_ + i * kC;
  const float* clb = clb_ + i * kC;
  const float* cow = cow_ + i * kC * kC;
  float* WL = wts + (long long)i * WTS_STRIDE;
  __shared__ float red2[2];

  int jstd = (c >> 3) * 1024 + d * 8 + (c & 7);  // std matrix u16 index for (c,d)

  // ---- SA: Wsa_pre = Wo_sa @ Wv_sa, fold ln gamma/beta ----
  float acc = 0.f;
  for (int m = 0; m < kC; m++) acc += sow[d * kC + m] * saw[(256 + m) * kC + c];
  float t1 = redsum128(acc * slb[c] + sow[d * kC + c] * sab[256 + c], red2);
  if (c == 0) WL[BSA + d] = t1 + sob[d];
  ((unsigned short*)(WL + WSA2))[jstd] = f2h(acc * slg[c]);

  // ---- Q (x0.25 fold) ----
  float wq = caw[d * kC + c];
  float t2 = redsum128(wq * clb[c], red2);
  if (c == 0) WL[BQ + d] = 0.25f * (t2 + cab[d]);
  ((unsigned short*)(WL + WQ2))[jstd] = f2h(0.25f * wq * clg[c]);

  // ---- K -> WKU [h][c][o-pairs] ----
  float wk = caw[(kC + d) * kC + c];
  float t3 = redsum128(wk * clb[c], red2);
  if (c == 0) WL[BK + d] = t3 + cab[kC + d];
  {
    int h = d >> 4, o = d & 15;
    ((unsigned short*)(WL + WKU))[h * 2048 + c * 16 + o] = f2h(wk * clg[c]);
  }

  // ---- V ----
  float wv = caw[(2 * kC + d) * kC + c];
  float t4 = redsum128(wv * clb[c], red2);
  if (c == 0) WL[BV + d] = t4 + cab[2 * kC + d];
  ((unsigned short*)(WL + WV2))[jstd] = f2h(wv * clg[c]);

  // ---- O (no fold, just pack) ----
  ((unsigned short*)(WL + WO2))[jstd] = f2h(cow[d * kC + c]);
}

// ---------------- kernel 3: bilinear warp + per-(bin,pixel) LN stats + nearest mask ----------------
__global__ __launch_bounds__(256) void k_warp(const float* __restrict__ f2t,
                                              const float* __restrict__ coords,
                                              float* __restrict__ F2, float* __restrict__ mu,
                                              float* __restrict__ sig, float* __restrict__ maskout) {
  int wave = threadIdx.x >> 6, lane = threadIdx.x & 63;
  int pix = blockIdx.x * 4 + wave;
  int b = blockIdx.y;
  long long bp = (long long)b * kP + pix;
  float cx = coords[bp * 2], cy = coords[bp * 2 + 1];
  cx = (cx < -1.f) ? -2.f : cx;
  cx = (cx > 1.f) ? 2.f : cx;
  cy = (cy < -1.f) ? -2.f : cy;
  cy = (cy > 1.f) ? 2.f : cy;
  float gx = (cx + 1.f) * 0.5f * (float)(kW - 1);
  float gy = (cy + 1.f) * 0.5f * (float)(kH - 1);
  float x0f = floorf(gx), y0f = floorf(gy);
  float wx = gx - x0f, wy = gy - y0f;
  int x0 = (int)x0f, y0 = (int)y0f;
  int x1 = x0 + 1, y1 = y0 + 1;
  float vx0 = (x0 >= 0 && x0 < kW) ? 1.f : 0.f;
  float vx1 = (x1 >= 0 && x1 < kW) ? 1.f : 0.f;
  float vy0 = (y0 >= 0 && y0 < kH) ? 1.f : 0.f;
  float vy1 = (y1 >= 0 && y1 < kH) ? 1.f : 0.f;
  int x0c = min(max(x0, 0), kW - 1), x1c = min(max(x1, 0), kW - 1);
  int y0c = min(max(y0, 0), kH - 1), y1c = min(max(y1, 0), kH - 1);
  float w00 = (1.f - wy) * (1.f - wx) * vx0 * vy0;
  float w01 = (1.f - wy) * wx * vx1 * vy0;
  float w10 = wy * (1.f - wx) * vx0 * vy1;
  float w11 = wy * wx * vx1 * vy1;
  const float2* r00 = (const float2*)(f2t + (y0c * kW + x0c) * kC);
  const float2* r01 = (const float2*)(f2t + (y0c * kW + x1c) * kC);
  const float2* r10 = (const float2*)(f2t + (y1c * kW + x0c) * kC);
  const float2* r11 = (const float2*)(f2t + (y1c * kW + x1c) * kC);
  float2 g00 = r00[lane], g01 = r01[lane], g10 = r10[lane], g11 = r11[lane];
  float v0 = w00 * g00.x + w01 * g01.x + w10 * g10.x + w11 * g11.x;
  float v1 = w00 * g00.y + w01 * g01.y + w10 * g10.y + w11 * g11.y;
  float s = v0 + v1, s2 = v0 * v0 + v1 * v1;
#pragma unroll
  for (int off = 32; off > 0; off >>= 1) {
    s += __shfl_xor(s, off);
    s2 += __shfl_xor(s2, off);
  }
  float m = s * (1.f / 128.f);
  float var = s2 * (1.f / 128.f) - m * m;
  float rs = rsqrtf(var + 1e-5f);
  float2 o;
  o.x = (v0 - m) * rs;
  o.y = (v1 - m) * rs;
  ((float2*)(F2 + bp * kC))[lane] = o;
  if (lane == 0) {
    mu[bp] = m;
    sig[bp] = sqrtf(var + 1e-5f);
    int xi = (int)rintf(gx), yi = (int)rintf(gy);
    maskout[bp] = (xi >= 0 && xi < kW && yi >= 0 && yi < kH) ? 1.f : 0.f;
  }
}

// ---------------- kernel 4: SSIM volume, rolling 3x3 column sums ----------------
__global__ __launch_bounds__(256) void k_ssim(const float* __restrict__ f1t,
                                              const float* __restrict__ F2,
                                              const float* __restrict__ mu,
                                              const float* __restrict__ sig,
                                              float* __restrict__ ssimout) {
  const int lane = threadIdx.x & 63;
  const int y = blockIdx.x * 4 + (threadIdx.x >> 6);
  const int b = blockIdx.y;
  const int ym = (y == 0) ? 1 : y - 1;
  const int yp = (y == kH - 1) ? kH - 2 : y + 1;
  const long long bb = (long long)b * kP;
  const float* f1m = f1t + (ym * kW) * kC + 2 * lane;
  const float* f10 = f1t + (y * kW) * kC + 2 * lane;
  const float* f1p = f1t + (yp * kW) * kC + 2 * lane;
  const float* F2m = F2 + (bb + ym * kW) * kC + 2 * lane;
  const float* F20 = F2 + (bb + y * kW) * kC + 2 * lane;
  const float* F2p = F2 + (bb + yp * kW) * kC + 2 * lane;
  const float* mum = mu + bb + ym * kW;
  const float* mu0 = mu + bb + y * kW;
  const float* mup = mu + bb + yp * kW;
  const float* sgm = sig + bb + ym * kW;
  const float* sg0 = sig + bb + y * kW;
  const float* sgp = sig + bb + yp * kW;
  float* outrow = ssimout + bb + y * kW;

  f2v C[3][5];

  auto colsum = [&](int x, f2v* Cc) {
    f2v am = *(const f2v*)(f1m + (size_t)x * kC);
    f2v a0 = *(const f2v*)(f10 + (size_t)x * kC);
    f2v ap = *(const f2v*)(f1p + (size_t)x * kC);
    f2v fm = *(const f2v*)(F2m + (size_t)x * kC);
    f2v f0 = *(const f2v*)(F20 + (size_t)x * kC);
    f2v fp = *(const f2v*)(F2p + (size_t)x * kC);
    f2v wm = fm * sgm[x] + mum[x];
    f2v w0 = f0 * sg0[x] + mu0[x];
    f2v wp = fp * sgp[x] + mup[x];
    Cc[0] = am + a0 + ap;
    Cc[1] = wm + w0 + wp;
    Cc[2] = am * am + a0 * a0 + ap * ap;
    Cc[3] = wm * wm + w0 * w0 + wp * wp;
    Cc[4] = am * wm + a0 * w0 + ap * wp;
  };

  auto emit = [&](int xo, f2v s0, f2v s1, f2v s2, f2v s3, f2v s4) {
    const float inv9 = 1.f / 9.f;
    f2v mx = s0 * inv9, my = s1 * inv9;
    f2v vx = s2 * inv9 - mx * mx;
    f2v vy = s3 * inv9 - my * my;
    f2v vxy = s4 * inv9 - mx * my;
    f2v num = (2.f * mx * my + 1e-4f) * (2.f * vxy + 9e-4f);
    f2v den = (mx * mx + my * my + 1e-4f) * (vx + vy + 9e-4f);
    f2v val = (1.f - num / den) * 0.5f;
    float t = fminf(fmaxf(val.x, 0.f), 1.f) + fminf(fmaxf(val.y, 0.f), 1.f);
#pragma unroll
    for (int o = 32; o > 0; o >>= 1) t += __shfl_xor(t, o);
    if (lane == 0) outrow[xo] = t * (1.f / 128.f);
  };

  colsum(0, C[0]);
  colsum(1, C[1]);
  emit(0, C[0][0] + 2.f * C[1][0], C[0][1] + 2.f * C[1][1], C[0][2] + 2.f * C[1][2],
       C[0][3] + 2.f * C[1][3], C[0][4] + 2.f * C[1][4]);
#pragma unroll 3
  for (int x = 2; x < kW; ++x) {
    colsum(x, C[x % 3]);
    emit(x - 1, C[0][0] + C[1][0] + C[2][0], C[0][1] + C[1][1] + C[2][1],
         C[0][2] + C[1][2] + C[2][2], C[0][3] + C[1][3] + C[2][3],
         C[0][4] + C[1][4] + C[2][4]);
  }
  emit(kW - 1, C[0][0] + 2.f * C[2][0], C[0][1] + 2.f * C[2][1], C[0][2] + 2.f * C[2][2],
       C[0][3] + 2.f * C[2][3], C[0][4] + 2.f * C[2][4]);
}

// ---------------- kernel 5: argmin over bins -> lowest_cost ----------------
__global__ __launch_bounds__(256) void k_argmin(const float* __restrict__ ssim,
                                                float* __restrict__ lc) {
  int pix = blockIdx.x * 256 + threadIdx.x;  // 7680 exact
  float best = ssim[pix];
  int bi = 0;
  for (int b = 1; b < kNB; b++) {
    float v = ssim[b * kP + pix];
    if (v < best) { best = v; bi = b; }
  }
  float depth = expf(-0.69314718f + (5.2983174f * (float)bi) / 63.0f);
  lc[pix] = 1.f / depth;
}

// ---------------- kernel 6: fused 6-layer transformer, 1 pixel / wave, no barriers ----
// (round-8 plateau: MFMA scores + u ^4h swizzle; VALU ~47% + L2 weight stream ~56%
// per-XCD + LDS-capped 8 waves/CU — co-limited; 2px/wave and 2-wave/px both regressed)

__device__ __forceinline__ f2v gemmW(int l, const unsigned* __restrict__ inb,
                                     const unsigned* __restrict__ W, float b0, float b1) {
  float a0 = b0, a1 = b1, c0 = 0.f, c1 = 0.f;  // 4 chains (even/odd j-chunks)
  const unsigned* wp = W + l * 8;
#pragma unroll
  for (int j = 0; j < 16; j += 2) {
    uint4 inA = *(const uint4*)(inb + 4 * j);
    uint4 inB = *(const uint4*)(inb + 4 * j + 4);
    uint4 wa = *(const uint4*)(wp + j * 512);
    uint4 wc = *(const uint4*)(wp + j * 512 + 4);
    uint4 wa2 = *(const uint4*)(wp + j * 512 + 512);
    uint4 wc2 = *(const uint4*)(wp + j * 512 + 516);
    a0 = fdot2(inA.x, wa.x, a0);  a0 = fdot2(inA.y, wa.y, a0);
    a0 = fdot2(inA.z, wa.z, a0);  a0 = fdot2(inA.w, wa.w, a0);
    a1 = fdot2(inA.x, wc.x, a1);  a1 = fdot2(inA.y, wc.y, a1);
    a1 = fdot2(inA.z, wc.z, a1);  a1 = fdot2(inA.w, wc.w, a1);
    c0 = fdot2(inB.x, wa2.x, c0); c0 = fdot2(inB.y, wa2.y, c0);
    c0 = fdot2(inB.z, wa2.z, c0); c0 = fdot2(inB.w, wa2.w, c0);
    c1 = fdot2(inB.x, wc2.x, c1); c1 = fdot2(inB.y, wc2.y, c1);
    c1 = fdot2(inB.z, wc2.z, c1); c1 = fdot2(inB.w, wc2.w, c1);
  }
  f2v r; r.x = a0 + c0; r.y = a1 + c1; return r;
}

__device__ __forceinline__ void ln_store(int l, f2v X, unsigned* xhq) {
  float s = X.x + X.y, s2 = X.x * X.x + X.y * X.y;
#pragma unroll
  for (int o = 32; o > 0; o >>= 1) { s += __shfl_xor(s, o); s2 += __shfl_xor(s2, o); }
  float m = s * 0.0078125f;
  float var = s2 * 0.0078125f - m * m;
  float rs = rsqrtf(var + 1e-5f);
  xhq[l] = pkrtz((X.x - m) * rs, (X.y - m) * rs);
}

__global__ __launch_bounds__(64) void k_attn(const float* __restrict__ F2g,
                                             const float* __restrict__ f1t,
                                             const float* __restrict__ wts,
                                             const float* __restrict__ cab_out,
                                             float* __restrict__ attn_out) {
  // F2s: [64 bins][64 u32 f16x2], XOR-swizzled: phys col = col ^ (4*(bin&15))
  __shared__ __align__(16) unsigned F2s[64 * 64];
  // upb: u (f16x2 [8h][64], col ^ 4h) -> p (f32 [64b][8h]) / rawh -> wbar ([8h][64], col ^ 4h)
  __shared__ __align__(16) unsigned upb[512];
  __shared__ __align__(16) unsigned xhq[64];  // xhat, later q (f16x2 c-pairs)

  const int l = threadIdx.x;
  const int pix = blockIdx.x;

  // ---- load this pixel's F2hat (f32 global) -> f16x2 swizzled LDS ----
  {
#pragma unroll 4
    for (int r = 0; r < 64; ++r) {
      float2 v = *(const float2*)(F2g + ((long long)r * kP + pix) * kC + 2 * l);
      F2s[r * 64 + (l ^ (4 * (r & 15)))] = pkrtz(v.x, v.y);
    }
  }
  f2v X;
  { float2 xv = ((const float2*)(f1t + (long long)pix * kC))[l]; X.x = xv.x; X.y = xv.y; }
  wb();

  float chsum = 0.f;
  float* pf = (float*)upb;
  const int mrow = l & 31;   // bin row within tile (also MFMA C col = head for n<8)
  const int kg = l >> 5;     // MFMA k-group
  const int rbase = 4 * kg;  // MFMA C row base

  for (int ly = 0; ly < kNL; ++ly) {
    const float* WL = wts + (long long)ly * WTS_STRIDE;

    // ---- LN(SA) -> xhq ; SA gemm ; residual ----
    ln_store(l, X, xhq);
    wb();
    {
      float2 bv = ((const float2*)(WL + BSA))[l];
      f2v o = gemmW(l, xhq, (const unsigned*)(WL + WSA2), bv.x, bv.y);
      X += o;
    }
    wb();
    // ---- LN(CA) -> xhq ; Q gemm ----
    ln_store(l, X, xhq);
    wb();
    f2v q;
    {
      float2 bv = ((const float2*)(WL + BQ))[l];
      q = gemmW(l, xhq, (const unsigned*)(WL + WQ2), bv.x, bv.y);
    }
    if (ly == kNL - 1) {  // k-bias contribution to raw: full dot q.bk
      float2 bk = ((const float2*)(WL + BK))[l];
      float cp = q.x * bk.x + q.y * bk.y;
#pragma unroll
      for (int o = 32; o > 0; o >>= 1) cp += __shfl_xor(cp, o);
      chsum = cp;
    }
    xhq[l] = pkrtz(q.x, q.y);  // qpk (d-pairs == o-pairs)
    wb();

    // ---- U: u[h][c-pair l] = sum_o q[h*16+o] * Wk'[h*16+o][c]; store col ^ 4h ----
    {
      const unsigned* KU = (const unsigned*)(WL + WKU);
#pragma unroll
      for (int h = 0; h < kNH; ++h) {
        uint4 q0 = *(const uint4*)(xhq + h * 8);      // o-pairs 0..3 (broadcast)
        uint4 q1 = *(const uint4*)(xhq + h * 8 + 4);  // o-pairs 4..7
        const unsigned* w0 = KU + (h * 128 + 2 * l) * 8;
        uint4 a0 = ((const uint4*)w0)[0], a1 = ((const uint4*)w0)[1];
        uint4 b0 = ((const uint4*)w0)[2], b1 = ((const uint4*)w0)[3];  // c = 2l+1
        float u0 = 0.f, u1 = 0.f, u2 = 0.f, u3 = 0.f;
        u0 = fdot2(q0.x, a0.x, u0); u0 = fdot2(q0.y, a0.y, u0);
        u0 = fdot2(q0.z, a0.z, u0); u0 = fdot2(q0.w, a0.w, u0);
        u2 = fdot2(q1.x, a1.x, u2); u2 = fdot2(q1.y, a1.y, u2);
        u2 = fdot2(q1.z, a1.z, u2); u2 = fdot2(q1.w, a1.w, u2);
        u1 = fdot2(q0.x, b0.x, u1); u1 = fdot2(q0.y, b0.y, u1);
        u1 = fdot2(q0.z, b0.z, u1); u1 = fdot2(q0.w, b0.w, u1);
        u3 = fdot2(q1.x, b1.x, u3); u3 = fdot2(q1.y, b1.y, u3);
        u3 = fdot2(q1.z, b1.z, u3); u3 = fdot2(q1.w, b1.w, u3);
        upb[h * 64 + (l ^ (4 * h))] = pkrtz(u0 + u2, u1 + u3);
      }
    }
    wb();

    // ---- scores via MFMA: C[bin][head] = F2[64x128] @ u[128x8] ----
    fx16 acc0 = (fx16)0.f, acc1 = (fx16)0.f;
    {
      const int hn = mrow & 7;          // clamp head for n>=8 lanes (dup cols, ignored)
      const int sw = 4 * (mrow & 15);   // same swizzle for bin and bin+32
      const int usw = 4 * hn;           // u row swizzle
#pragma unroll
      for (int kc = 0; kc < 8; ++kc) {
        const int cp = kc * 8 + kg * 4;  // u32 column of channel k0 = kc*16+kg*8
        h8 Bv = *(const h8*)(upb + hn * 64 + (cp ^ usw));
        h8 A0 = *(const h8*)(F2s + mrow * 64 + (cp ^ sw));
        h8 A1 = *(const h8*)(F2s + (mrow + 32) * 64 + (cp ^ sw));
        acc0 = __builtin_amdgcn_mfma_f32_32x32x16_f16(A0, Bv, acc0, 0, 0, 0);
        acc1 = __builtin_amdgcn_mfma_f32_32x32x16_f16(A1, Bv, acc1, 0, 0, 0);
      }
    }
    if (ly == kNL - 1) {
      // raw[bin] = sum_h sc[bin][h] + chsum; redistribute via pf as rawh[8][64]
      wb();
      if (mrow < 8) {
#pragma unroll
        for (int r = 0; r < 16; ++r) {
          int row = (r & 3) + 8 * (r >> 2) + rbase;
          pf[mrow * 64 + row] = acc0[r];
          pf[mrow * 64 + 32 + row] = acc1[r];
        }
      }
      wb();
      float rsum = chsum;
#pragma unroll
      for (int h = 0; h < kNH; ++h) rsum += pf[h * 64 + l];
      attn_out[(long long)pix * 64 + l] = rsum;
      return;
    }
    // ---- softmax over bins: head h lives in lanes {h, h+32} (16+16 rows each) ----
    {
      float mx = acc0[0];
#pragma unroll
      for (int r = 0; r < 16; ++r) { mx = fmaxf(mx, acc0[r]); mx = fmaxf(mx, acc1[r]); }
      mx = fmaxf(mx, __shfl_xor(mx, 32));
      float pv0[16], pv1[16];
      float sm = 0.f;
#pragma unroll
      for (int r = 0; r < 16; ++r) {
        pv0[r] = __expf(acc0[r] - mx); sm += pv0[r];
        pv1[r] = __expf(acc1[r] - mx); sm += pv1[r];
      }
      sm += __shfl_xor(sm, 32);
      float inv = 1.f / sm;
      wb();  // all u (B-frag) reads complete before pf overwrites upb
      if (mrow < 8) {
#pragma unroll
        for (int r = 0; r < 16; ++r) {
          int row = (r & 3) + 8 * (r >> 2) + rbase;
          pf[row * 8 + mrow] = pv0[r] * inv;
          pf[(32 + row) * 8 + mrow] = pv1[r] * inv;
        }
      }
    }
    wb();
    // ---- wbar[h][c] = sum_b p[b][h]*F2[b][c]; lane owns 4 ch, half-wave owns 32 bins ----
    {
      const int half = l >> 5, lb = l & 31;
      f2v wA[8], wB[8];
#pragma unroll
      for (int h = 0; h < kNH; ++h) { wA[h] = (f2v)0.f; wB[h] = (f2v)0.f; }
#pragma unroll 2
      for (int t = 0; t < 32; ++t) {
        int b = half * 32 + t;
        uint2 fv = *(const uint2*)(F2s + b * 64 + ((2 * lb) ^ (4 * (b & 15))));
        f2v fA = h2f(fv.x), fB = h2f(fv.y);
        float4 pA = *(const float4*)(pf + b * 8);
        float4 pB = *(const float4*)(pf + b * 8 + 4);
        wA[0] += fA * pA.x; wB[0] += fB * pA.x;
        wA[1] += fA * pA.y; wB[1] += fB * pA.y;
        wA[2] += fA * pA.z; wB[2] += fB * pA.z;
        wA[3] += fA * pA.w; wB[3] += fB * pA.w;
        wA[4] += fA * pB.x; wB[4] += fB * pB.x;
        wA[5] += fA * pB.y; wB[5] += fB * pB.y;
        wA[6] += fA * pB.z; wB[6] += fB * pB.z;
        wA[7] += fA * pB.w; wB[7] += fB * pB.w;
      }
      // combine halves
#pragma unroll
      for (int h = 0; h < kNH; ++h) {
        wA[h].x += __shfl_xor(wA[h].x, 32);
        wA[h].y += __shfl_xor(wA[h].y, 32);
        wB[h].x += __shfl_xor(wB[h].x, 32);
        wB[h].y += __shfl_xor(wB[h].y, 32);
      }
      wb();
      // write packed wbar into upb ([8h][64], col swizzle ^ 4h); halves split h-ranges
#pragma unroll
      for (int hh = 0; hh < 4; ++hh) {
        int h = half * 4 + hh;
        uint2 pk;
        pk.x = pkrtz(wA[h].x, wA[h].y);
        pk.y = pkrtz(wB[h].x, wB[h].y);
        *(uint2*)(upb + h * 64 + ((2 * lb) ^ (4 * h))) = pk;
      }
    }
    wb();
    // ---- AO: ao[d] = wbar[h(d)] . Wv'[:,d] + bv (4 chains) ----
    {
      const int h = l >> 3;  // d=2l -> head
      const unsigned* wrow = upb + h * 64;
      const unsigned* WV = (const unsigned*)(WL + WV2) + l * 8;
      float2 bv = ((const float2*)(WL + BV))[l];
      float a0 = bv.x, a1 = bv.y, c0 = 0.f, c1 = 0.f;
      const int sw = 4 * h;
#pragma unroll
      for (int j = 0; j < 16; j += 2) {
        uint4 inA = *(const uint4*)(wrow + ((4 * j) ^ sw));
        uint4 inB = *(const uint4*)(wrow + ((4 * j + 4) ^ sw));
        uint4 wa = *(const uint4*)(WV + j * 512);
        uint4 wc = *(const uint4*)(WV + j * 512 + 4);
        uint4 wa2 = *(const uint4*)(WV + j * 512 + 512);
        uint4 wc2 = *(const uint4*)(WV + j * 512 + 516);
        a0 = fdot2(inA.x, wa.x, a0);  a0 = fdot2(inA.y, wa.y, a0);
        a0 = fdot2(inA.z, wa.z, a0);  a0 = fdot2(inA.w, wa.w, a0);
        a1 = fdot2(inA.x, wc.x, a1);  a1 = fdot2(inA.y, wc.y, a1);
        a1 = fdot2(inA.z, wc.z, a1);  a1 = fdot2(inA.w, wc.w, a1);
        c0 = fdot2(inB.x, wa2.x, c0); c0 = fdot2(inB.y, wa2.y, c0);
        c0 = fdot2(inB.z, wa2.z, c0); c0 = fdot2(inB.w, wa2.w, c0);
        c1 = fdot2(inB.x, wc2.x, c1); c1 = fdot2(inB.y, wc2.y, c1);
        c1 = fdot2(inB.z, wc2.z, c1); c1 = fdot2(inB.w, wc2.w, c1);
      }
      xhq[l] = pkrtz(a0 + c0, a1 + c1);
    }
    wb();
    // ---- O: X += ao @ Wo^T + bo ----
    {
      float2 bv = ((const float2*)(cab_out + ly * kC))[l];
      f2v o = gemmW(l, xhq, (const unsigned*)(WL + WO2), bv.x, bv.y);
      X += o;
    }
    wb();
  }
}

// ---------------- launch ----------------
extern "C" void kernel_launch(void* const* d_in, const int* in_sizes, int n_in, void* d_out,
                              int out_size, void* d_ws, size_t ws_size, hipStream_t stream) {
  (void)in_sizes; (void)n_in; (void)out_size; (void)ws_size;
  const float* feat1 = (const float*)d_in[0];
  const float* feat2 = (const float*)d_in[1];
  const float* coords = (const float*)d_in[2];
  const float* sa_in_w = (const float*)d_in[3];
  const float* sa_in_b = (const float*)d_in[4];
  const float* sa_out_w = (const float*)d_in[5];
  const float* sa_out_b = (const float*)d_in[6];
  const float* sa_ln_g = (const float*)d_in[7];
  const float* sa_ln_b = (const float*)d_in[8];
  const float* ca_in_w = (const float*)d_in[9];
  const float* ca_in_b = (const float*)d_in[10];
  const float* ca_out_w = (const float*)d_in[11];
  const float* ca_out_b = (const float*)d_in[12];
  const float* ca_ln_g = (const float*)d_in[13];
  const float* ca_ln_b = (const float*)d_in[14];

  float* out = (float*)d_out;
  float* ws = (float*)d_ws;
  float* f1t = ws + OFF_F1T;
  float* f2t = ws + OFF_F2T;
  float* F2 = ws + OFF_F2;
  float* mu = ws + OFF_MU;
  float* sig = ws + OFF_SIG;
  float* wts = ws + OFF_WTS;

  float* att = out + OUT_ATT;
  float* mask = out + OUT_MASK;
  float* lc = out + OUT_LC;
  float* ssim = out + OUT_SSIM;

  dim3 gt(240, 4);
  k_transpose<<<gt, 256, 0, stream>>>(feat1, feat2, f1t, f2t);
  k_fold<<<kNL * 128, 128, 0, stream>>>(sa_in_w, sa_in_b, sa_out_w, sa_out_b, sa_ln_g, sa_ln_b,
                                        ca_in_w, ca_in_b, ca_ln_g, ca_ln_b, ca_out_w, wts);
  dim3 g1(1920, 64);
  k_warp<<<g1, 256, 0, stream>>>(f2t, coords, F2, mu, sig, mask);
  dim3 g2(12, 64);
  k_ssim<<<g2, 256, 0, stream>>>(f1t, F2, mu, sig, ssim);
  k_argmin<<<30, 256, 0, stream>>>(ssim, lc);
  k_attn<<<kP, 64, 0, stream>>>(F2, f1t, wts, ca_out_b, att);
}